// Round 1
// baseline (9.584 us; speedup 1.0000x reference)
//
#include <hip/hip_runtime.h>
#include <math.h>

// Izhikevich 'RS' params + constants from the reference
#define A_P 0.02f
#define B_P 0.2f
#define C_P -65.0f
#define D_P 8.0f
#define I_TONIC -1.5f
#define V_SPIKE 30.0f
#define RATE_DECAY 0.95f
#define OSC_FREQ 0.04f
#define PC_TAU 0.125f
#define PC_SUBSTEPS 8
#define TWO_PI 6.28318530717958647692f

__global__ void __launch_bounds__(64)
SpikingInferiorOlive_kernel(const float* __restrict__ sensory_surprise,
                            const float* __restrict__ motor_mismatch,
                            const float* __restrict__ cerebellar_pe,
                            const float* __restrict__ prev_sensory,
                            const float* __restrict__ prev_motor,
                            const float* __restrict__ osc_phase,
                            const float* __restrict__ v0,
                            const float* __restrict__ u0,
                            const float* __restrict__ rate0,
                            const float* __restrict__ noise,   // [10][8]
                            const float* __restrict__ pc_m0,
                            float* __restrict__ out)           // 16 floats
{
    if (threadIdx.x != 0) return;

    const float s   = sensory_surprise[0];
    const float m   = motor_mismatch[0];
    const float cpe = cerebellar_pe[0];

    const float delta_sensory = fabsf(s - prev_sensory[0]);
    const float sensory_error = fminf(1.0f, delta_sensory + s * 0.3f);
    const float delta_motor   = fabsf(m - prev_motor[0]);
    const float motor_error   = fminf(1.0f, delta_motor + m * 0.3f);

    const float phase = osc_phase[0] + OSC_FREQ;
    const float osc   = 0.15f * sinf(TWO_PI * phase);

    const float raw_cf = sensory_error * 0.4f + motor_error * 0.4f + cpe * 0.2f;
    const bool  is_cs  = raw_cf > 0.2f;
    const float climbing_fiber = is_cs ? fminf(1.0f, raw_cf * 1.5f)
                                       : fmaxf(0.0f, raw_cf + osc);

    // Input currents per neuron
    float I[8];
    I[0] = sensory_error * 15.0f;
    I[1] = delta_sensory * 12.0f;
    I[2] = sensory_error * 8.0f;
    I[3] = osc * 5.0f + 2.0f;
    I[4] = motor_error * 15.0f;
    I[5] = delta_motor * 12.0f;
    I[6] = motor_error * 8.0f;
    I[7] = climbing_fiber * 10.0f;

    float v[8], u[8], r[8];
#pragma unroll
    for (int i = 0; i < 8; ++i) { v[i] = v0[i]; u[i] = u0[i]; r[i] = rate0[i]; }

    const float one_minus_decay = 1.0f - RATE_DECAY;
#pragma unroll
    for (int t = 0; t < 10; ++t) {
#pragma unroll
        for (int i = 0; i < 8; ++i) {
            const float Ii = I[i] + noise[t * 8 + i] * 0.3f + I_TONIC;
            const float dv = 0.04f * v[i] * v[i] + 5.0f * v[i] + 140.0f - u[i] + Ii;
            const float du = A_P * (B_P * v[i] - u[i]);
            v[i] += dv;
            u[i] += du;
            const bool sp = (v[i] >= V_SPIKE);
            if (sp) { v[i] = C_P; u[i] += D_P; }
            r[i] = RATE_DECAY * r[i] + one_minus_decay * (sp ? 1.0f : 0.0f);
        }
    }

    // TwoCompColumn predictive coding: 2 channels x 4 neurons, 8 substeps
    float mem[8], drive[8];
#pragma unroll
    for (int i = 0; i < 8; ++i) {
        mem[i]   = pc_m0[i];
        drive[i] = (i < 4) ? sensory_error : motor_error;
    }
#pragma unroll
    for (int t = 0; t < PC_SUBSTEPS; ++t) {
#pragma unroll
        for (int i = 0; i < 8; ++i) mem[i] += PC_TAU * (drive[i] - mem[i]);
    }

    const float pe0 = (mem[0] + mem[1] + mem[2] + mem[3]) * 0.25f;
    const float pe1 = (mem[4] + mem[5] + mem[6] + mem[7]) * 0.25f;
    const float prec0 = 1.0f / (1.0f + pe0 * pe0);
    const float prec1 = 1.0f / (1.0f + pe1 * pe1);
    const float free_energy = 0.5f * (prec0 * pe0 * pe0 + prec1 * pe1 * pe1);
    const float prediction_error = 0.5f * (fabsf(pe0) + fabsf(pe1));

    float rate_mean = 0.0f;
#pragma unroll
    for (int i = 0; i < 8; ++i) rate_mean += r[i];
    rate_mean *= 0.125f;

    out[0] = sensory_error;
    out[1] = motor_error;
    out[2] = climbing_fiber;
    out[3] = is_cs ? 1.0f : 0.0f;
    out[4] = prediction_error;
    out[5] = (prec0 + prec1) * 0.5f;
    out[6] = free_energy;
    out[7] = rate_mean;
#pragma unroll
    for (int i = 0; i < 8; ++i) out[8 + i] = r[i];
}

extern "C" void kernel_launch(void* const* d_in, const int* in_sizes, int n_in,
                              void* d_out, int out_size, void* d_ws, size_t ws_size,
                              hipStream_t stream) {
    (void)in_sizes; (void)n_in; (void)d_ws; (void)ws_size; (void)out_size;
    SpikingInferiorOlive_kernel<<<1, 64, 0, stream>>>(
        (const float*)d_in[0],  // sensory_surprise
        (const float*)d_in[1],  // motor_mismatch
        (const float*)d_in[2],  // cerebellar_pe
        (const float*)d_in[3],  // prev_sensory
        (const float*)d_in[4],  // prev_motor
        (const float*)d_in[5],  // osc_phase
        (const float*)d_in[6],  // v0
        (const float*)d_in[7],  // u0
        (const float*)d_in[8],  // rate0
        (const float*)d_in[9],  // noise [10][8]
        (const float*)d_in[10], // pc_m0
        (float*)d_out);
}